// Round 10
// baseline (332.558 us; speedup 1.0000x reference)
//
#include <hip/hip_runtime.h>
#include <cmath>

#define BB 8
#define NN 5000
#define EE 80000
#define NODE_IN 32
#define EDGE_IN 16
#define HIDDEN 128
#define EMBED 64
#define BN (BB*NN)     // 40000
#define BE (BB*EE)     // 640000

typedef unsigned short u16;
typedef __attribute__((ext_vector_type(8))) __bf16 bf16x8;
typedef __attribute__((ext_vector_type(4))) float f32x4;

__device__ __forceinline__ float waveSum(float v){
  #pragma unroll
  for(int o=32;o;o>>=1) v += __shfl_xor(v,o);
  return v;
}
__device__ __forceinline__ float waveMax(float v){
  #pragma unroll
  for(int o=32;o;o>>=1) v = fmaxf(v,__shfl_xor(v,o));
  return v;
}
__device__ __forceinline__ int rlanei(int v, int l){
  return __builtin_amdgcn_readlane(v, l);
}
__device__ __forceinline__ float rlanef(float v, int l){
  return __uint_as_float(__builtin_amdgcn_readlane(__float_as_uint(v), l));
}
__device__ __forceinline__ unsigned pack_bf2(float a0, float a1){
  unsigned u0 = __float_as_uint(a0), u1 = __float_as_uint(a1);
  unsigned r0 = (u0 + 0x7fffu + ((u0>>16)&1u)) >> 16;
  unsigned r1 = (u1 + 0x7fffu + ((u1>>16)&1u)) & 0xffff0000u;
  return r0 | r1;
}
__device__ __forceinline__ u16 bf16r(float x){
  unsigned u = __float_as_uint(x);
  return (u16)((u + 0x7fffu + ((u>>16)&1u)) >> 16);
}
__device__ __forceinline__ float bflo(unsigned h){ return __uint_as_float(h<<16); }
__device__ __forceinline__ float bfhi(unsigned h){ return __uint_as_float(h & 0xffff0000u); }
__device__ __forceinline__ bf16x8 ld8_or_zero(const u16* p, bool pred){
  uint4 v = pred ? *(const uint4*)p : make_uint4(0u,0u,0u,0u);
  return *(bf16x8*)&v;
}
// monotone fp32<->uint key for atomicMax
__device__ __forceinline__ unsigned fkey(float x){
  unsigned s = __float_as_uint(x);
  return (s & 0x80000000u) ? ~s : (s | 0x80000000u);
}
__device__ __forceinline__ float funkey(unsigned k){
  return __uint_as_float((k & 0x80000000u) ? (k & 0x7fffffffu) : ~k);
}

// K1: prep — wae, w_s1/w_d1, BT1 [64][136] bf16, BT2 [256][72] bf16, AT1e [128][16] bf16
__launch_bounds__(256)
__global__ void k_prep(const float* We0, const float* ae0,
                       const float* We1, const float* ae1,
                       const float* W1g, const float* asrc1, const float* adst1,
                       const float* mlpW1,
                       float* wae, float* ws1, float* wd1,
                       u16* BT1u, u16* BT2u, u16* AT1e){
  int t = threadIdx.x;
  if(blockIdx.x == 0){
    if(t < 16){
      float a = 0.f;
      for(int k=0;k<HIDDEN;k++) a += We0[t*HIDDEN+k]*ae0[k];
      wae[t] = a;
    } else if(t < 32){
      int j = t-16;
      float a = 0.f;
      for(int k=0;k<EMBED;k++) a += We1[j*EMBED+k]*ae1[k];
      wae[16+j] = a;
    }
    if(t < 128){
      float s = 0.f, d = 0.f;
      for(int k=0;k<EMBED;k++){
        float w = W1g[t*EMBED+k];
        s += w*asrc1[k];
        d += w*adst1[k];
      }
      ws1[t] = s; wd1[t] = d;
    }
    for(int i=t; i<2048; i+=256){
      int o = i >> 4, k = i & 15;
      AT1e[o*16 + k] = bf16r(mlpW1[(128+k)*HIDDEN + o]);
    }
  } else {
    #pragma unroll
    for(int ii=0; ii<6; ii++){
      int idx = (blockIdx.x-1)*1536 + ii*256 + t;
      if(idx < 8192){
        int c = idx >> 7, k = idx & 127;           // BT1[c][k] = W1g[k][c]
        BT1u[c*136 + k] = bf16r(W1g[k*EMBED + c]);
      } else {
        int i2 = idx - 8192;
        int d = i2 >> 6, j = i2 & 63;              // BT2[d][j]
        float v = (d < 128) ? mlpW1[j*HIDDEN + d] : mlpW1[(64+j)*HIDDEN + (d-128)];
        BT2u[d*72 + j] = bf16r(v);
      }
    }
  }
}

// K2: LayerNorm(node_x) -> H0 bf16-packed, s0, d0.
__launch_bounds__(256)
__global__ void k_node(const float* __restrict__ x, const float* __restrict__ g,
                       const float* __restrict__ bb, const float* __restrict__ W,
                       const float* __restrict__ asrc, const float* __restrict__ adst,
                       unsigned* __restrict__ H0u, float* __restrict__ S0o, float* __restrict__ D0o){
  int t = threadIdx.x;
  int w = t>>6, lane = t&63;
  float w0r[NODE_IN], w1r[NODE_IN];
  #pragma unroll
  for(int j=0;j<NODE_IN;j++){
    w0r[j] = W[j*HIDDEN + 2*lane];
    w1r[j] = W[j*HIDDEN + 2*lane + 1];
  }
  float gl = (lane<NODE_IN)? g[lane] : 0.f;
  float bl = (lane<NODE_IN)? bb[lane] : 0.f;
  float asl0 = asrc[2*lane], asl1 = asrc[2*lane+1];
  float adl0 = adst[2*lane], adl1 = adst[2*lane+1];
  for(int nb = blockIdx.x; nb < BN/4; nb += gridDim.x){
    int n = nb*4 + w;
    float xv = (lane<NODE_IN)? x[n*NODE_IN+lane] : 0.f;
    float s  = waveSum(xv);
    float s2 = waveSum(xv*xv);
    float mu = s*(1.f/NODE_IN);
    float var = s2*(1.f/NODE_IN) - mu*mu;
    float inv = 1.0f / sqrtf(var + 1e-5f);
    float nx = (lane<NODE_IN)? ((xv-mu)*inv*gl + bl) : 0.f;
    float a0=0.f, a1=0.f;
    #pragma unroll
    for(int j=0;j<NODE_IN;j++){
      float r = rlanef(nx, j);
      a0 += r*w0r[j];
      a1 += r*w1r[j];
    }
    H0u[(size_t)n*64 + lane] = pack_bf2(a0, a1);
    float sv = waveSum(a0*asl0 + a1*asl1);
    float dv = waveSum(a0*adl0 + a1*adl1);
    if(lane==0){ S0o[n]=sv; D0o[n]=dv; }
  }
}

// K3: LayerNorm(edge_attr) scattered into CSR order; EA bf16; LG0 = e0 + S0[src]
__launch_bounds__(256)
__global__ void k_edge(const float* __restrict__ ein, const float* __restrict__ g,
                       const float* __restrict__ bb, const float* __restrict__ wae,
                       const int* __restrict__ EPOS, const int* __restrict__ ei,
                       const float* __restrict__ S0,
                       u16* __restrict__ EAb, float* __restrict__ LG0p, float* __restrict__ E1p){
  int ge = blockIdx.x*256 + threadIdx.x;   // < BE exactly
  int b = ge / EE, e = ge - b*EE;
  int gp = b*EE + EPOS[e];
  float v[EDGE_IN];
  const float4* p = (const float4*)(ein + (size_t)ge*EDGE_IN);
  float4 q0=p[0], q1=p[1], q2=p[2], q3=p[3];
  v[0]=q0.x; v[1]=q0.y; v[2]=q0.z; v[3]=q0.w;
  v[4]=q1.x; v[5]=q1.y; v[6]=q1.z; v[7]=q1.w;
  v[8]=q2.x; v[9]=q2.y; v[10]=q2.z; v[11]=q2.w;
  v[12]=q3.x; v[13]=q3.y; v[14]=q3.z; v[15]=q3.w;
  float s=0.f, s2=0.f;
  #pragma unroll
  for(int j=0;j<EDGE_IN;j++){ s += v[j]; s2 += v[j]*v[j]; }
  float mu = s*(1.f/EDGE_IN);
  float var = s2*(1.f/EDGE_IN) - mu*mu;
  float inv = 1.0f / sqrtf(var + 1e-5f);
  float e0=0.f, e1=0.f;
  #pragma unroll
  for(int j=0;j<EDGE_IN;j++){
    float nv = (v[j]-mu)*inv*g[j] + bb[j];
    v[j] = nv;
    e0 += nv*wae[j];
    e1 += nv*wae[16+j];
  }
  uint4 w0 = make_uint4(pack_bf2(v[0],v[1]), pack_bf2(v[2],v[3]),
                        pack_bf2(v[4],v[5]), pack_bf2(v[6],v[7]));
  uint4 w1 = make_uint4(pack_bf2(v[8],v[9]), pack_bf2(v[10],v[11]),
                        pack_bf2(v[12],v[13]), pack_bf2(v[14],v[15]));
  uint4* q = (uint4*)&EAb[(size_t)gp*16];
  q[0] = w0; q[1] = w1;
  LG0p[gp] = e0 + S0[b*NN + ei[e]];     // fold src-term of layer-0 logits
  E1p[gp]  = e1;
}

// K4b: histogram of dst
__global__ void k_count(const int* __restrict__ ei, int* __restrict__ cnt){
  int e = blockIdx.x*256 + threadIdx.x;
  if(e < EE) atomicAdd(&cnt[ei[EE+e]], 1);
}

// K4c: exclusive scan of 5000 counts
__launch_bounds__(1024)
__global__ void k_scan(int* __restrict__ off, int* __restrict__ cur){
  __shared__ int part[1024];
  int t = threadIdx.x;
  int loc[5]; int s=0;
  int base = t*5;
  #pragma unroll
  for(int k=0;k<5;k++){ int idx=base+k; int c=(idx<NN)? cur[idx]:0; loc[k]=s; s+=c; }
  part[t]=s;
  __syncthreads();
  for(int o=1;o<1024;o<<=1){
    int v = (t>=o)? part[t-o] : 0;
    __syncthreads();
    part[t] += v;
    __syncthreads();
  }
  int pre = (t>0)? part[t-1] : 0;
  #pragma unroll
  for(int k=0;k<5;k++){
    int idx=base+k;
    if(idx<NN){ int o2 = pre+loc[k]; off[idx]=o2; cur[idx]=o2; }
  }
  if(t==0) off[NN] = EE;
}

// K4d: scatter edges into CSR
__global__ void k_fill(const int* __restrict__ ei, int* __restrict__ cur,
                       int* __restrict__ csrc, int* __restrict__ cdst,
                       int* __restrict__ ceid, int* __restrict__ epos){
  int e = blockIdx.x*256 + threadIdx.x;
  if(e < EE){
    int d = ei[EE+e];
    int pos = atomicAdd(&cur[d], 1);
    csrc[pos] = ei[e];
    cdst[pos] = d;
    ceid[pos] = e;
    epos[e] = pos;
  }
}

// K5: GAT0 aggregation over bf16 H0 + ELU + fused S1/D1 epilogue. Logits via LG0.
__launch_bounds__(256)
__global__ void k_gat0(const unsigned* __restrict__ H0u, const float* __restrict__ D0,
                       const float* __restrict__ LG0p,
                       const int* __restrict__ off, const int* __restrict__ csrc,
                       const float* __restrict__ bias,
                       const float* __restrict__ WS1, const float* __restrict__ WD1,
                       unsigned* __restrict__ HELUu, float* __restrict__ S1o, float* __restrict__ D1o){
  int t = threadIdx.x, w = t>>6, lane = t&63;
  int b = blockIdx.x & 7, c = blockIdx.x >> 3;
  int n = c*4 + w;
  int gid = b*NN + n;
  int base = off[n], deg = off[n+1]-base;
  const float* lg0b = LG0p + b*EE;
  const unsigned* h0b = H0u + (size_t)b*NN*64;
  float dv = D0[gid];
  float acc0=0.f, acc1=0.f;
  if(deg > 0){
    if(deg <= 64){
      float lg = -INFINITY; int sidx = 0;
      if(lane < deg){
        sidx = csrc[base+lane];
        float xx = lg0b[base+lane] + dv;
        lg = xx>0.f ? xx : 0.2f*xx;
      }
      float m = waveMax(lg);
      float ex = (lane<deg)? __expf(lg-m) : 0.f;
      float den = waveSum(ex);
      float al = ex / (den + 1e-16f);
      int nb8 = (deg+7)>>3;
      for(int b8=0;b8<nb8;b8++){
        int i0 = b8*8;
        int ss[8]; float aa[8]; unsigned hh[8];
        #pragma unroll
        for(int kk=0;kk<8;kk++){ ss[kk]=rlanei(sidx, i0+kk); aa[kk]=rlanef(al, i0+kk); }
        #pragma unroll
        for(int kk=0;kk<8;kk++){ hh[kk]=h0b[ss[kk]*64 + lane]; }
        #pragma unroll
        for(int kk=0;kk<8;kk++){ acc0 += aa[kk]*bflo(hh[kk]); acc1 += aa[kk]*bfhi(hh[kk]); }
      }
    } else {
      float m = -INFINITY;
      for(int i=lane;i<deg;i+=64){
        float xx = lg0b[base+i] + dv;
        xx = xx>0.f ? xx : 0.2f*xx;
        m = fmaxf(m, xx);
      }
      m = waveMax(m);
      float den = 0.f;
      for(int i=lane;i<deg;i+=64){
        float xx = lg0b[base+i] + dv;
        xx = xx>0.f ? xx : 0.2f*xx;
        den += __expf(xx-m);
      }
      den = waveSum(den) + 1e-16f;
      for(int i=0;i<deg;i++){
        int s = csrc[base+i];
        float xx = lg0b[base+i] + dv;
        xx = xx>0.f ? xx : 0.2f*xx;
        float a = __expf(xx-m)/den;
        unsigned h = h0b[s*64 + lane];
        acc0 += a*bflo(h);
        acc1 += a*bfhi(h);
      }
    }
  }
  float2 bi = *(const float2*)&bias[2*lane];
  float v0 = acc0 + bi.x;
  float v1 = acc1 + bi.y;
  v0 = v0>0.f ? v0 : (__expf(v0)-1.f);
  v1 = v1>0.f ? v1 : (__expf(v1)-1.f);
  HELUu[(size_t)gid*64 + lane] = pack_bf2(v0, v1);
  float2 wsv = *(const float2*)&WS1[2*lane];
  float2 wdv = *(const float2*)&WD1[2*lane];
  float sv1 = waveSum(v0*wsv.x + v1*wsv.y);
  float dv1 = waveSum(v0*wdv.x + v1*wdv.y);
  if(lane==0){ S1o[gid]=sv1; D1o[gid]=dv1; }
}

// K5b: LG1 = E1p + S1[src], coalesced; S1 slice (20KB/graph) is L1-resident.
__global__ void k_lg1(const float* __restrict__ S1, const int* __restrict__ csrc,
                      float* __restrict__ LG1){
  int p = blockIdx.x*256 + threadIdx.x;   // < BE
  int b = p / EE, pp = p - b*EE;
  LG1[p] += S1[b*NN + csrc[pp]];
}

// K6: H1 = HELU @ W1g via MFMA. H1 out bf16 u16[n][64].
__launch_bounds__(256)
__global__ void k_h1(const unsigned* __restrict__ HELUu, const u16* __restrict__ BT1,
                     u16* __restrict__ H1u){
  __shared__ u16 Ald[64*136];
  __shared__ u16 Bld[64*136];
  int t = threadIdx.x;
  int n0 = blockIdx.x*64;
  #pragma unroll
  for(int ii=0; ii<4; ii++){
    int c2 = ii*256 + t;
    int r = c2 >> 4, q = c2 & 15;
    *(uint4*)&Ald[r*136 + q*8] = ((const uint4*)(HELUu + (size_t)(n0+r)*64))[q];
  }
  for(int i=t; i<1088; i+=256) ((uint4*)Bld)[i] = ((const uint4*)BT1)[i];
  __syncthreads();
  int w = t>>6, lane = t&63;
  int lo = lane & 15, hi = lane >> 4;
  f32x4 acc0 = {0.f,0.f,0.f,0.f}, acc1 = acc0, acc2 = acc0, acc3 = acc0;
  #pragma unroll
  for(int ks=0; ks<4; ks++){
    bf16x8 a = *(const bf16x8*)&Ald[(w*16+lo)*136 + ks*32 + hi*8];
    bf16x8 b0 = *(const bf16x8*)&Bld[(0*16+lo)*136 + ks*32 + hi*8];
    bf16x8 b1 = *(const bf16x8*)&Bld[(1*16+lo)*136 + ks*32 + hi*8];
    bf16x8 b2 = *(const bf16x8*)&Bld[(2*16+lo)*136 + ks*32 + hi*8];
    bf16x8 b3 = *(const bf16x8*)&Bld[(3*16+lo)*136 + ks*32 + hi*8];
    acc0 = __builtin_amdgcn_mfma_f32_16x16x32_bf16(a, b0, acc0, 0,0,0);
    acc1 = __builtin_amdgcn_mfma_f32_16x16x32_bf16(a, b1, acc1, 0,0,0);
    acc2 = __builtin_amdgcn_mfma_f32_16x16x32_bf16(a, b2, acc2, 0,0,0);
    acc3 = __builtin_amdgcn_mfma_f32_16x16x32_bf16(a, b3, acc3, 0,0,0);
  }
  int rowb = n0 + w*16 + hi*4;
  #pragma unroll
  for(int r=0;r<4;r++){
    H1u[(size_t)(rowb+r)*64 +  0 + lo] = bf16r(acc0[r]);
    H1u[(size_t)(rowb+r)*64 + 16 + lo] = bf16r(acc1[r]);
    H1u[(size_t)(rowb+r)*64 + 32 + lo] = bf16r(acc2[r]);
    H1u[(size_t)(rowb+r)*64 + 48 + lo] = bf16r(acc3[r]);
  }
}

// K7: GAT1 aggregation over bf16 H1, logits via LG1; fused mean/max pooling atomics.
__launch_bounds__(256)
__global__ void k_gat1(const u16* __restrict__ H1u, const float* __restrict__ D1,
                       const float* __restrict__ LG1,
                       const int* __restrict__ off, const int* __restrict__ csrc,
                       const float* __restrict__ bias, float* __restrict__ out,
                       float* __restrict__ PSUM, unsigned* __restrict__ PMAXu){
  __shared__ float lsum[4][64];
  __shared__ unsigned lkey[4][64];
  int t = threadIdx.x, w = t>>6, lane = t&63;
  int b = blockIdx.x & 7, c = blockIdx.x >> 3;
  int n = c*4 + w;
  int gid = b*NN + n;
  int base = off[n], deg = off[n+1]-base;
  const float* e1b = LG1 + b*EE;
  const u16* h1b = H1u + (size_t)b*NN*64;
  float dv = D1[gid];
  float acc = 0.f;
  if(deg > 0){
    if(deg <= 64){
      float lg = -INFINITY; int sidx = 0;
      if(lane < deg){
        sidx = csrc[base+lane];
        float xx = e1b[base+lane] + dv;
        lg = xx>0.f ? xx : 0.2f*xx;
      }
      float m = waveMax(lg);
      float ex = (lane<deg)? __expf(lg-m) : 0.f;
      float den = waveSum(ex);
      float al = ex / (den + 1e-16f);
      int nb8 = (deg+7)>>3;
      for(int b8=0;b8<nb8;b8++){
        int i0 = b8*8;
        int ss[8]; float aa[8]; unsigned hh[8];
        #pragma unroll
        for(int kk=0;kk<8;kk++){ ss[kk]=rlanei(sidx, i0+kk); aa[kk]=rlanef(al, i0+kk); }
        #pragma unroll
        for(int kk=0;kk<8;kk++){ hh[kk]=h1b[ss[kk]*64 + lane]; }
        #pragma unroll
        for(int kk=0;kk<8;kk++){ acc += aa[kk]*__uint_as_float(hh[kk]<<16); }
      }
    } else {
      float m = -INFINITY;
      for(int i=lane;i<deg;i+=64){
        float xx = e1b[base+i] + dv;
        xx = xx>0.f ? xx : 0.2f*xx;
        m = fmaxf(m, xx);
      }
      m = waveMax(m);
      float den = 0.f;
      for(int i=lane;i<deg;i+=64){
        float xx = e1b[base+i] + dv;
        xx = xx>0.f ? xx : 0.2f*xx;
        den += __expf(xx-m);
      }
      den = waveSum(den) + 1e-16f;
      for(int i=0;i<deg;i++){
        int s = csrc[base+i];
        float xx = e1b[base+i] + dv;
        xx = xx>0.f ? xx : 0.2f*xx;
        float a = __expf(xx-m)/den;
        acc += a*__uint_as_float(((unsigned)h1b[s*64 + lane])<<16);
      }
    }
  }
  float o = acc + bias[lane];
  out[(size_t)gid*EMBED + lane] = o;
  lsum[w][lane] = o;
  lkey[w][lane] = fkey(o);
  __syncthreads();
  if(t < 64){
    float S = lsum[0][t]+lsum[1][t]+lsum[2][t]+lsum[3][t];
    unsigned K = max(max(lkey[0][t],lkey[1][t]), max(lkey[2][t],lkey[3][t]));
    atomicAdd(&PSUM[b*64+t], S);
    atomicMax(&PMAXu[b*64+t], K);
  }
}

// K9: ctx from atomically-built partials; ctx_proj = b1 + ctx @ W1[144:272]
__launch_bounds__(128)
__global__ void k_ctxp(const float* __restrict__ PSUM, const unsigned* __restrict__ PMAXu,
                       const float* __restrict__ W1, const float* __restrict__ b1,
                       float* __restrict__ CTXP){
  int b = blockIdx.x, c = threadIdx.x;
  __shared__ float cl[128];
  if(c < 64) cl[c] = PSUM[b*64+c] * (1.f/NN);
  else       cl[c] = funkey(PMAXu[b*64 + (c-64)]);
  __syncthreads();
  float a = b1[c];
  for(int j=0;j<128;j++) a += cl[j]*W1[(144+j)*HIDDEN + c];
  CTXP[b*128+c] = a;
}

// K10: PS/PD = EMB @ [W1src|W1dst] via MFMA + 0.5*ctxp fold; bf16 u16[n][128].
__launch_bounds__(256)
__global__ void k_psd(const float* __restrict__ EMB, const u16* __restrict__ BT2,
                      const float* __restrict__ CTXP,
                      u16* __restrict__ PSu, u16* __restrict__ PDu){
  __shared__ u16 Ald[64*72];
  __shared__ u16 Bld[256*72];
  int t = threadIdx.x;
  int n0 = blockIdx.x*64;
  #pragma unroll
  for(int ii=0; ii<2; ii++){
    int c2 = ii*256 + t;
    int r = c2 >> 3, q = c2 & 7;
    const float4* src = (const float4*)(EMB + (size_t)(n0+r)*EMBED + q*8);
    float4 f0 = src[0], f1 = src[1];
    uint4 pk = make_uint4(pack_bf2(f0.x,f0.y), pack_bf2(f0.z,f0.w),
                          pack_bf2(f1.x,f1.y), pack_bf2(f1.z,f1.w));
    *(uint4*)&Ald[r*72 + q*8] = pk;
  }
  for(int i=t; i<2304; i+=256) ((uint4*)Bld)[i] = ((const uint4*)BT2)[i];
  __syncthreads();
  int w = t>>6, lane = t&63;
  int lo = lane & 15, hi = lane >> 4;
  f32x4 acc[16];
  #pragma unroll
  for(int i=0;i<16;i++) acc[i] = (f32x4){0.f,0.f,0.f,0.f};
  #pragma unroll
  for(int ks=0; ks<2; ks++){
    bf16x8 a = *(const bf16x8*)&Ald[(w*16+lo)*72 + ks*32 + hi*8];
    #pragma unroll
    for(int nt=0; nt<16; nt++){
      bf16x8 b = *(const bf16x8*)&Bld[(nt*16+lo)*72 + ks*32 + hi*8];
      acc[nt] = __builtin_amdgcn_mfma_f32_16x16x32_bf16(a, b, acc[nt], 0,0,0);
    }
  }
  int rowb = n0 + w*16 + hi*4;
  #pragma unroll
  for(int r=0;r<4;r++){
    int row = rowb + r;
    int bg = row / NN;
    const float* cp = CTXP + bg*128;
    #pragma unroll
    for(int nt=0; nt<16; nt++){
      int dim = (nt & 7)*16 + lo;
      u16 u = bf16r(acc[nt][r] + 0.5f*cp[dim]);
      if(nt < 8) PSu[(size_t)row*HIDDEN + dim] = u;
      else       PDu[(size_t)row*HIDDEN + dim] = u;
    }
  }
}

// K11: per-edge MLP via MFMA. 32 edges/wave (2 groups of 16), unrolled so
// group-1 PS gathers overlap group-0 compute. PS cooperatively staged via LDS.
__launch_bounds__(256)
__global__ void k_final(const u16* __restrict__ EAb, const int* __restrict__ csrc,
                        const int* __restrict__ cdst, const int* __restrict__ ceid,
                        const u16* __restrict__ PS, const u16* __restrict__ PD,
                        const u16* __restrict__ AT1e,
                        const float* __restrict__ W2, const float* __restrict__ b2,
                        float* __restrict__ out){
  __shared__ unsigned ldsPS[4][16][66];
  int t = threadIdx.x, w = t>>6, lane = t&63;
  int lo = lane & 15, hi = lane >> 4;
  int b = blockIdx.x & 7, c = blockIdx.x >> 3;
  int pg = c*128 + w*32;                      // wave: 32 edges, 2 groups of 16
  bf16x8 afr[8];
  #pragma unroll
  for(int mt=0;mt<8;mt++) afr[mt] = ld8_or_zero(&AT1e[(mt*16+lo)*16 + hi*8], hi<2);
  float4 w2r[8];
  #pragma unroll
  for(int mt=0;mt<8;mt++) w2r[mt] = *(const float4*)&W2[mt*16 + hi*4];
  float bias2 = b2[0];
  const unsigned* PSb32 = (const unsigned*)(PS + (size_t)b*NN*HIDDEN);
  const u16* PDb = PD + (size_t)b*NN*HIDDEN;
  int sv = (lane<32)? csrc[pg+lane] : 0;      // both groups' src indices
  #pragma unroll
  for(int g=0; g<2; g++){
    int pgg = pg + g*16;
    unsigned vs[16];
    #pragma unroll
    for(int k=0;k<16;k++){
      int sk = rlanei(sv, g*16+k);
      vs[k] = PSb32[(size_t)sk*64 + lane];
    }
    int d = cdst[pgg + lo];
    const u16* qr = PDb + (size_t)d*HIDDEN + hi*4;
    uint2 pdv[8];
    #pragma unroll
    for(int mt=0;mt<8;mt++) pdv[mt] = *(const uint2*)(qr + mt*16);
    bf16x8 bfr = ld8_or_zero(&EAb[((size_t)b*EE + pgg + lo)*16 + hi*8], hi<2);
    #pragma unroll
    for(int k=0;k<16;k++) ldsPS[w][k][lane] = vs[k];
    f32x4 acc[8];
    #pragma unroll
    for(int mt=0;mt<8;mt++){
      f32x4 z = {0.f,0.f,0.f,0.f};
      acc[mt] = __builtin_amdgcn_mfma_f32_16x16x32_bf16(afr[mt], bfr, z, 0,0,0);
    }
    float qp = 0.f;
    #pragma unroll
    for(int mt=0;mt<8;mt++){
      uint2 psv = *(const uint2*)&ldsPS[w][lo][hi*2 + mt*8];
      float h0 = acc[mt][0] + bflo(psv.x) + bflo(pdv[mt].x);
      float h1 = acc[mt][1] + bfhi(psv.x) + bfhi(pdv[mt].x);
      float h2 = acc[mt][2] + bflo(psv.y) + bflo(pdv[mt].y);
      float h3 = acc[mt][3] + bfhi(psv.y) + bfhi(pdv[mt].y);
      qp += fmaxf(h0,0.f)*w2r[mt].x + fmaxf(h1,0.f)*w2r[mt].y
          + fmaxf(h2,0.f)*w2r[mt].z + fmaxf(h3,0.f)*w2r[mt].w;
    }
    qp += __shfl_xor(qp, 16);
    qp += __shfl_xor(qp, 32);
    if(lane < 16){
      int ev = ceid[pgg + lane];
      out[(size_t)b*EE + ev] = qp + bias2;
    }
  }
}

extern "C" void kernel_launch(void* const* d_in, const int* in_sizes, int n_in,
                              void* d_out, int out_size, void* d_ws, size_t ws_size,
                              hipStream_t stream) {
  const float* node_x   = (const float*)d_in[0];
  const float* edge_attr= (const float*)d_in[1];
  const int*   edge_idx = (const int*)d_in[2];
  const float* ln_ng    = (const float*)d_in[3];
  const float* ln_nb    = (const float*)d_in[4];
  const float* ln_eg    = (const float*)d_in[5];
  const float* ln_eb    = (const float*)d_in[6];
  const float* g0_W     = (const float*)d_in[7];
  const float* g0_We    = (const float*)d_in[8];
  const float* g0_asrc  = (const float*)d_in[9];
  const float* g0_adst  = (const float*)d_in[10];
  const float* g0_ae    = (const float*)d_in[11];
  const float* g0_b     = (const float*)d_in[12];
  const float* g1_W     = (const float*)d_in[13];
  const float* g1_We    = (const float*)d_in[14];
  const float* g1_asrc  = (const float*)d_in[15];
  const float* g1_adst  = (const float*)d_in[16];
  const float* g1_ae    = (const float*)d_in[17];
  const float* g1_b     = (const float*)d_in[18];
  const float* mlp_W1   = (const float*)d_in[19];
  const float* mlp_b1   = (const float*)d_in[20];
  const float* mlp_W2   = (const float*)d_in[21];
  const float* mlp_b2   = (const float*)d_in[22];
  float* out = (float*)d_out;

  // workspace layout (32-bit words)
  float* ws   = (float*)d_ws;
  float* EAp  = ws;                       // region — EAb16
  float* LG0p = EAp  + (size_t)BE*EDGE_IN;// 640,000 (was E0p)
  float* E1p  = LG0p + BE;                // 640,000 (becomes LG1 in-place)
  float* H0   = E1p  + BE;                // region — H0u then PS
  float* HELU = H0   + (size_t)BN*HIDDEN; // region — HELUu then PD
  float* H1   = HELU + (size_t)BN*HIDDEN; // region — H1u16
  float* EMBa = H1   + (size_t)BN*EMBED;  // 2,560,000
  float* S0   = EMBa + (size_t)BN*EMBED;  // 40,000
  float* D0   = S0 + BN;
  float* S1   = D0 + BN;
  float* D1   = S1 + BN;
  float* CTX  = D1 + BN;                  // 1024 (unused)
  float* CTXP = CTX + 1024;               // 1024
  float* WAE  = CTXP + 1024;              // 32
  int* CSR_OFF = (int*)(WAE + 32);        // 5004
  int* CSR_CUR = CSR_OFF + (NN+4);        // 5000
  int* CSR_SRC = CSR_CUR + NN;            // 80000
  int* CSR_DST = CSR_SRC + EE;            // 80000
  int* CSR_EID = CSR_DST + EE;            // 80000
  int* EPOS    = CSR_EID + EE;            // 80000
  float* WS1   = (float*)(EPOS + EE);     // 128
  float* WD1   = WS1 + 128;               // 128
  u16* BT1u    = (u16*)(WD1 + 128);       // 64*136 u16
  u16* BT2u    = BT1u + 64*136;           // 256*72 u16
  float* PSUM  = (float*)(BT2u + 256*72); // 512 floats
  unsigned* PMAXu = (unsigned*)(PSUM + 512); // 512 uints
  u16* AT1e    = (u16*)(PMAXu + 512);     // 2048 u16
  u16* EAb16      = (u16*)EAp;            // BE*16 u16
  unsigned* H0u   = (unsigned*)H0;        // BN*64 dwords
  unsigned* HELUu = (unsigned*)HELU;      // BN*64 dwords
  u16*      H1u   = (u16*)H1;             // BN*64 u16
  u16* PS = (u16*)H0;                     // bf16 [node][128] (after H0u consumed)
  u16* PD = (u16*)HELU;

  hipMemsetAsync(CSR_CUR, 0, NN*sizeof(int), stream);
  hipMemsetAsync(PSUM, 0, 1024*sizeof(int), stream);   // PSUM + PMAX keys
  k_prep<<<17, 256, 0, stream>>>(g0_We, g0_ae, g1_We, g1_ae, g1_W, g1_asrc, g1_adst,
                                 mlp_W1, WAE, WS1, WD1, BT1u, BT2u, AT1e);
  k_count<<<(EE+255)/256, 256, 0, stream>>>(edge_idx, CSR_CUR);
  k_scan<<<1, 1024, 0, stream>>>(CSR_OFF, CSR_CUR);
  k_fill<<<(EE+255)/256, 256, 0, stream>>>(edge_idx, CSR_CUR, CSR_SRC, CSR_DST, CSR_EID, EPOS);
  k_node<<<1024, 256, 0, stream>>>(node_x, ln_ng, ln_nb, g0_W, g0_asrc, g0_adst, H0u, S0, D0);
  k_edge<<<BE/256, 256, 0, stream>>>(edge_attr, ln_eg, ln_eb, WAE, EPOS, edge_idx, S0,
                                     EAb16, LG0p, E1p);
  k_gat0<<<BN/4, 256, 0, stream>>>(H0u, D0, LG0p, CSR_OFF, CSR_SRC, g0_b, WS1, WD1, HELUu, S1, D1);
  k_lg1<<<BE/256, 256, 0, stream>>>(S1, CSR_SRC, E1p);
  k_h1<<<BN/64, 256, 0, stream>>>(HELUu, BT1u, H1u);
  k_gat1<<<BN/4, 256, 0, stream>>>(H1u, D1, E1p, CSR_OFF, CSR_SRC, g1_b, EMBa, PSUM, PMAXu);
  k_ctxp<<<BB, 128, 0, stream>>>(PSUM, PMAXu, mlp_W1, mlp_b1, CTXP);
  k_psd<<<BN/64, 256, 0, stream>>>(EMBa, BT2u, CTXP, PS, PD);
  k_final<<<BE/128, 256, 0, stream>>>(EAb16, CSR_SRC, CSR_DST, CSR_EID, PS, PD, AT1e, mlp_W2, mlp_b2, out);
}